// Round 1
// baseline (465.095 us; speedup 1.0000x reference)
//
#include <hip/hip_runtime.h>

#define MD 4
#define DD 9          // 2*MD+1
#define KK 81         // DD*DD
#define B_ 4
#define C_ 128
#define H_ 192
#define W_ 192
#define HW (H_ * W_)

// out[b,c,y,x] = (1/C) * sum_{p,o} first[b,(p)*9+(o),y,x] * second[b,c,y+p-4,x+o-4]
//
// Block: 256 threads = 16 x-groups (x-vec 4) x 16 channel-groups (8 ch each).
// Tile: 1 y-row, 64 x-pixels, all 128 channels. Grid: (W/64, H, B) = (3,192,4).
// first slab (81 x 64 floats = 20.25 KB) staged in LDS once per block.

__global__ __launch_bounds__(256, 4)
void corr_transpose_kernel(const float* __restrict__ first,
                           const float* __restrict__ second,
                           float* __restrict__ out) {
  __shared__ __align__(16) float ldsF[KK * 64];

  const int xt0 = blockIdx.x * 64;   // 0,64,128
  const int y   = blockIdx.y;        // 0..191
  const int b   = blockIdx.z;        // 0..3

  const int tid = threadIdx.x;

  // ---- stage first[b, :, y, xt0..xt0+63] into LDS (coalesced float4) ----
  {
    const float* fbase = first + ((size_t)(b * KK) * H_ + y) * (size_t)W_ + xt0;
    for (int idx = tid; idx < KK * 16; idx += 256) {
      const int k  = idx >> 4;
      const int xi = (idx & 15) << 2;
      const float4 v =
          *reinterpret_cast<const float4*>(fbase + (size_t)k * HW + xi);
      *reinterpret_cast<float4*>(&ldsF[k * 64 + xi]) = v;
    }
  }
  __syncthreads();

  const int xg = tid & 15;
  const int cg = tid >> 4;
  const int x0 = xt0 + xg * 4;
  const bool interior = (x0 >= 4) && (x0 + 8 <= W_);

  const float* secB = second + (size_t)b * C_ * HW;
  float*       outB = out    + (size_t)b * C_ * HW;

  for (int cc = 0; cc < 2; ++cc) {
    const int c0 = cg * 8 + cc * 4;

    float acc[4][4];
#pragma unroll
    for (int i = 0; i < 4; ++i)
#pragma unroll
      for (int j = 0; j < 4; ++j) acc[i][j] = 0.f;

    for (int p = 0; p < DD; ++p) {
      const int yy = y + p - MD;
      if (yy < 0 || yy >= H_) continue;   // uniform per block

      // first weights for this p-row: fo[o] = first[k=p*9+o][x0..x0+3]
      float4 fo[DD];
#pragma unroll
      for (int o = 0; o < DD; ++o)
        fo[o] = *reinterpret_cast<const float4*>(&ldsF[(p * DD + o) * 64 + xg * 4]);

#pragma unroll
      for (int ci = 0; ci < 4; ++ci) {
        const float* row = secB + ((size_t)(c0 + ci) * H_ + yy) * (size_t)W_;
        float s[12];
        if (interior) {
          const float4 a = *reinterpret_cast<const float4*>(row + x0 - 4);
          const float4 m = *reinterpret_cast<const float4*>(row + x0);
          const float4 e = *reinterpret_cast<const float4*>(row + x0 + 4);
          s[0] = a.x; s[1] = a.y; s[2]  = a.z; s[3]  = a.w;
          s[4] = m.x; s[5] = m.y; s[6]  = m.z; s[7]  = m.w;
          s[8] = e.x; s[9] = e.y; s[10] = e.z; s[11] = e.w;
        } else {
#pragma unroll
          for (int j = 0; j < 12; ++j) {
            const int xx = x0 - 4 + j;
            s[j] = (xx >= 0 && xx < W_) ? row[xx] : 0.f;
          }
        }
#pragma unroll
        for (int o = 0; o < DD; ++o) {
          acc[ci][0] = fmaf(fo[o].x, s[o + 0], acc[ci][0]);
          acc[ci][1] = fmaf(fo[o].y, s[o + 1], acc[ci][1]);
          acc[ci][2] = fmaf(fo[o].z, s[o + 2], acc[ci][2]);
          acc[ci][3] = fmaf(fo[o].w, s[o + 3], acc[ci][3]);
        }
      }
    }

    const float inv_c = 1.0f / (float)C_;
#pragma unroll
    for (int ci = 0; ci < 4; ++ci) {
      float4 v;
      v.x = acc[ci][0] * inv_c;
      v.y = acc[ci][1] * inv_c;
      v.z = acc[ci][2] * inv_c;
      v.w = acc[ci][3] * inv_c;
      *reinterpret_cast<float4*>(outB + ((size_t)(c0 + ci) * H_ + y) * (size_t)W_ + x0) = v;
    }
  }
}

extern "C" void kernel_launch(void* const* d_in, const int* in_sizes, int n_in,
                              void* d_out, int out_size, void* d_ws, size_t ws_size,
                              hipStream_t stream) {
  const float* first  = (const float*)d_in[0];
  const float* second = (const float*)d_in[1];
  float* out = (float*)d_out;

  dim3 grid(W_ / 64, H_, B_);
  corr_transpose_kernel<<<grid, 256, 0, stream>>>(first, second, out);
}

// Round 2
// 454.470 us; speedup vs baseline: 1.0234x; 1.0234x over previous
//
#include <hip/hip_runtime.h>

#define MD 4
#define DD 9          // 2*MD+1
#define KK 81         // DD*DD
#define B_ 4
#define C_ 128
#define H_ 192
#define W_ 192
#define HW (H_ * W_)

// out[b,c,y,x] = (1/C) * sum_{p,o} first[b,p*9+o,y,x] * second[b,c,y+p-4,x+o-4]
//
// Block: 256 threads = 16 x-groups (x-vec 4) x 16 channel-groups (8 ch each).
// Tile: 1 y-row, 64 x-pixels, all 128 channels. Grid: (W/64, H, B) = (3,192,4).
// first slab (81 x 64 floats = 20.25 KB) staged in LDS once per block.
// Register plan: acc[8][4]=32 + fo[9]x4=36 + s[12] transient + addr ~= 120 VGPR.
// __launch_bounds__(256,2): VGPR cap 256 -> no spill (round-1's (256,4) pinned
// 64 VGPR and spilled ~430 MB of scratch traffic: WRITE_SIZE 503MB vs 75.5MB out).

__global__ __launch_bounds__(256, 2)
void corr_transpose_kernel(const float* __restrict__ first,
                           const float* __restrict__ second,
                           float* __restrict__ out) {
  __shared__ __align__(16) float ldsF[KK * 64];

  const int xt0 = blockIdx.x * 64;   // 0,64,128
  const int y   = blockIdx.y;        // 0..191
  const int b   = blockIdx.z;        // 0..3
  const int tid = threadIdx.x;

  // ---- stage first[b, :, y, xt0..xt0+63] into LDS (coalesced float4) ----
  {
    const float* fbase = first + ((size_t)(b * KK) * H_ + y) * (size_t)W_ + xt0;
    for (int idx = tid; idx < KK * 16; idx += 256) {
      const int k  = idx >> 4;
      const int xi = (idx & 15) << 2;
      *reinterpret_cast<float4*>(&ldsF[k * 64 + xi]) =
          *reinterpret_cast<const float4*>(fbase + (size_t)k * HW + xi);
    }
  }
  __syncthreads();

  const int xg = tid & 15;
  const int cg = tid >> 4;
  const int x0 = xt0 + xg * 4;
  const bool interior = (x0 >= 4) && (x0 + 8 <= W_);
  const int cbase = cg * 8;

  const float* secB = second + (size_t)b * C_ * HW;
  float*       outB = out    + (size_t)b * C_ * HW;

  float acc[8][4];
#pragma unroll
  for (int i = 0; i < 8; ++i)
#pragma unroll
    for (int j = 0; j < 4; ++j) acc[i][j] = 0.f;

  for (int p = 0; p < DD; ++p) {
    const int yy = y + p - MD;
    if (yy < 0 || yy >= H_) continue;   // block-uniform branch

    // weights for this p-row, shared by all 8 channels of this thread
    float4 fo[DD];
#pragma unroll
    for (int o = 0; o < DD; ++o)
      fo[o] = *reinterpret_cast<const float4*>(&ldsF[(p * DD + o) * 64 + xg * 4]);

#pragma unroll
    for (int ci = 0; ci < 8; ++ci) {
      const float* row = secB + ((size_t)(cbase + ci) * H_ + yy) * (size_t)W_;
      float s[12];
      if (interior) {
        const float4 a = *reinterpret_cast<const float4*>(row + x0 - 4);
        const float4 m = *reinterpret_cast<const float4*>(row + x0);
        const float4 e = *reinterpret_cast<const float4*>(row + x0 + 4);
        s[0] = a.x; s[1] = a.y; s[2]  = a.z; s[3]  = a.w;
        s[4] = m.x; s[5] = m.y; s[6]  = m.z; s[7]  = m.w;
        s[8] = e.x; s[9] = e.y; s[10] = e.z; s[11] = e.w;
      } else {
#pragma unroll
        for (int j = 0; j < 12; ++j) {
          const int xx = x0 - 4 + j;
          s[j] = (xx >= 0 && xx < W_) ? row[xx] : 0.f;
        }
      }
#pragma unroll
      for (int o = 0; o < DD; ++o) {
        acc[ci][0] = fmaf(fo[o].x, s[o + 0], acc[ci][0]);
        acc[ci][1] = fmaf(fo[o].y, s[o + 1], acc[ci][1]);
        acc[ci][2] = fmaf(fo[o].z, s[o + 2], acc[ci][2]);
        acc[ci][3] = fmaf(fo[o].w, s[o + 3], acc[ci][3]);
      }
    }
  }

  const float inv_c = 1.0f / (float)C_;
#pragma unroll
  for (int ci = 0; ci < 8; ++ci) {
    float4 v;
    v.x = acc[ci][0] * inv_c;
    v.y = acc[ci][1] * inv_c;
    v.z = acc[ci][2] * inv_c;
    v.w = acc[ci][3] * inv_c;
    *reinterpret_cast<float4*>(outB + ((size_t)(cbase + ci) * H_ + y) * (size_t)W_ + x0) = v;
  }
}

extern "C" void kernel_launch(void* const* d_in, const int* in_sizes, int n_in,
                              void* d_out, int out_size, void* d_ws, size_t ws_size,
                              hipStream_t stream) {
  const float* first  = (const float*)d_in[0];
  const float* second = (const float*)d_in[1];
  float* out = (float*)d_out;

  dim3 grid(W_ / 64, H_, B_);
  corr_transpose_kernel<<<grid, 256, 0, stream>>>(first, second, out);
}

// Round 3
// 318.461 us; speedup vs baseline: 1.4604x; 1.4271x over previous
//
#include <hip/hip_runtime.h>

#define MD 4
#define DD 9          // 2*MD+1
#define KK 81         // DD*DD
#define B_ 4
#define C_ 128
#define H_ 192
#define W_ 192
#define HW (H_ * W_)
#define NWG (3 * H_ * B_)        // 2304 workgroups
#define PER_XCD (NWG / 8)        // 288

// out[b,c,y,x] = (1/C) * sum_{p,o} first[b,p*9+o,y,x] * second[b,c,y+p-4,x+o-4]
//
// Block: 256 threads = 16 x-groups (x-vec 4) x 16 channel-groups (8 ch each).
// Tile: 1 y-row, 64 x-pixels, all 128 channels.
// Grid: 1D 2304 with bijective XCD swizzle (y-fastest within an XCD chunk) so
// the 9-row second halo stays L2-resident per XCD (round-2: FETCH=702MB, ~9x
// second re-fetch because y-neighbors round-robined across 8 XCDs).
// Register plan: acc[8][4]=32 + fo[9]x4=36 + s[4ch staged]~48 + addr ~= 140.
// __launch_bounds__(256,1): cap 512 -> no spill (round-2's (256,2) pinned 128
// and spilled ~212MB: WRITE 287MB vs 75.5MB output).

__global__ __launch_bounds__(256, 1)
void corr_transpose_kernel(const float* __restrict__ first,
                           const float* __restrict__ second,
                           float* __restrict__ out) {
  __shared__ __align__(16) float ldsF[KK * 64];

  // ---- XCD-contiguous, y-fastest work decode (bijective, 2304 % 8 == 0) ----
  const int lin = blockIdx.x;
  const int wid = (lin & 7) * PER_XCD + (lin >> 3);
  const int y   = wid % H_;          // fastest: consecutive y on same XCD
  const int t   = wid / H_;          // 0..11
  const int xt0 = (t % 3) * 64;      // x-tile
  const int b   = t / 3;             // batch

  const int tid = threadIdx.x;

  // ---- stage first[b, :, y, xt0..xt0+63] into LDS (coalesced float4) ----
  {
    const float* fbase = first + ((size_t)(b * KK) * H_ + y) * (size_t)W_ + xt0;
    for (int idx = tid; idx < KK * 16; idx += 256) {
      const int k  = idx >> 4;
      const int xi = (idx & 15) << 2;
      *reinterpret_cast<float4*>(&ldsF[k * 64 + xi]) =
          *reinterpret_cast<const float4*>(fbase + (size_t)k * HW + xi);
    }
  }
  __syncthreads();

  const int xg = tid & 15;
  const int cg = tid >> 4;
  const int x0 = xt0 + xg * 4;
  const bool interior = (x0 >= 4) && (x0 + 8 <= W_);
  const int cbase = cg * 8;

  const float* secB = second + (size_t)b * C_ * HW;
  float*       outB = out    + (size_t)b * C_ * HW;

  float acc[8][4];
#pragma unroll
  for (int i = 0; i < 8; ++i)
#pragma unroll
    for (int j = 0; j < 4; ++j) acc[i][j] = 0.f;

  for (int p = 0; p < DD; ++p) {
    const int yy = y + p - MD;
    if (yy < 0 || yy >= H_) continue;   // block-uniform branch

    // weights for this p-row, shared by this thread's 8 channels
    float4 fo[DD];
#pragma unroll
    for (int o = 0; o < DD; ++o)
      fo[o] = *reinterpret_cast<const float4*>(&ldsF[(p * DD + o) * 64 + xg * 4]);

    // two sub-blocks of 4 channels: halves the concurrent-load live range
    for (int cc = 0; cc < 2; ++cc) {
#pragma unroll
      for (int ci = 0; ci < 4; ++ci) {
        const int ch = cbase + cc * 4 + ci;
        const float* row = secB + ((size_t)ch * H_ + yy) * (size_t)W_;
        float s[12];
        if (interior) {
          const float4 a = *reinterpret_cast<const float4*>(row + x0 - 4);
          const float4 m = *reinterpret_cast<const float4*>(row + x0);
          const float4 e = *reinterpret_cast<const float4*>(row + x0 + 4);
          s[0] = a.x; s[1] = a.y; s[2]  = a.z; s[3]  = a.w;
          s[4] = m.x; s[5] = m.y; s[6]  = m.z; s[7]  = m.w;
          s[8] = e.x; s[9] = e.y; s[10] = e.z; s[11] = e.w;
        } else {
#pragma unroll
          for (int j = 0; j < 12; ++j) {
            const int xx = x0 - 4 + j;
            s[j] = (xx >= 0 && xx < W_) ? row[xx] : 0.f;
          }
        }
        float* a4 = acc[cc * 4 + ci];
#pragma unroll
        for (int o = 0; o < DD; ++o) {
          a4[0] = fmaf(fo[o].x, s[o + 0], a4[0]);
          a4[1] = fmaf(fo[o].y, s[o + 1], a4[1]);
          a4[2] = fmaf(fo[o].z, s[o + 2], a4[2]);
          a4[3] = fmaf(fo[o].w, s[o + 3], a4[3]);
        }
      }
    }
  }

  const float inv_c = 1.0f / (float)C_;
#pragma unroll
  for (int ci = 0; ci < 8; ++ci) {
    float4 v;
    v.x = acc[ci][0] * inv_c;
    v.y = acc[ci][1] * inv_c;
    v.z = acc[ci][2] * inv_c;
    v.w = acc[ci][3] * inv_c;
    *reinterpret_cast<float4*>(outB + ((size_t)(cbase + ci) * H_ + y) * (size_t)W_ + x0) = v;
  }
}

extern "C" void kernel_launch(void* const* d_in, const int* in_sizes, int n_in,
                              void* d_out, int out_size, void* d_ws, size_t ws_size,
                              hipStream_t stream) {
  const float* first  = (const float*)d_in[0];
  const float* second = (const float*)d_in[1];
  float* out = (float*)d_out;

  corr_transpose_kernel<<<dim3(NWG), 256, 0, stream>>>(first, second, out);
}

// Round 4
// 90.565 us; speedup vs baseline: 5.1355x; 3.5164x over previous
//
#include <hip/hip_runtime.h>

#define MD 4
#define DD 9          // 2*MD+1
#define KK 81         // DD*DD
#define B_ 4
#define C_ 128
#define H_ 192
#define W_ 192
#define HW (H_ * W_)
#define NWG 4608      // 2 chalf * 3 xt * 192 y * 4 b
#define PER_XCD (NWG / 8)

// out[b,c,y,x] = (1/C) * sum_{p,o} first[b,p*9+o,y,x] * second[b,c,y+p-4,x+o-4]
//
// Block: 256 thr = 16 xg (x-vec4) x 16 cg (4 ch each) -> 64 ch, 64 x, 1 y.
// Grid 4608 = 2 ch-halves x 3 x-tiles x 192 y x 4 b, XCD-swizzled y-fastest.
// Software pipeline: 2-ch load groups; group g+1 / next-p loads issued while
// FMA-ing group g (round 3: VALUBusy 17%, latency exposed on every 12-load
// batch). Edge handling: clamped vector addrs + cndmask zero (round 3's
// divergent scalar path executed by every wave in 2/3 of blocks).
// (256,1): no VGPR pin -> no spill (rounds 1/2: pinned 64/128 -> 503/287 MB
// scratch writes; round 3 at 144 VGPR: WRITE == output exactly).

__device__ __forceinline__ void unpack12(float (&s)[12],
                                         const float4& A, const float4& M,
                                         const float4& E,
                                         bool edge, bool mA, bool mE) {
  s[0] = A.x; s[1] = A.y; s[2]  = A.z; s[3]  = A.w;
  s[4] = M.x; s[5] = M.y; s[6]  = M.z; s[7]  = M.w;
  s[8] = E.x; s[9] = E.y; s[10] = E.z; s[11] = E.w;
  if (edge) {                       // block-uniform branch; cndmask inside
    if (!mA) { s[0] = 0.f; s[1] = 0.f; s[2]  = 0.f; s[3]  = 0.f; }
    if (!mE) { s[8] = 0.f; s[9] = 0.f; s[10] = 0.f; s[11] = 0.f; }
  }
}

#define FMA_GROUP(accp, s)                                   \
  _Pragma("unroll")                                          \
  for (int o = 0; o < DD; ++o) {                             \
    accp[0] = fmaf(fo[o].x, s[o + 0], accp[0]);              \
    accp[1] = fmaf(fo[o].y, s[o + 1], accp[1]);              \
    accp[2] = fmaf(fo[o].z, s[o + 2], accp[2]);              \
    accp[3] = fmaf(fo[o].w, s[o + 3], accp[3]);              \
  }

__global__ __launch_bounds__(256, 1)
void corr_transpose_kernel(const float* __restrict__ first,
                           const float* __restrict__ second,
                           float* __restrict__ out) {
  __shared__ __align__(16) float ldsF[KK * 64];

  // bijective XCD swizzle (4608 % 8 == 0), y-fastest within an XCD chunk
  const int lin = blockIdx.x;
  const int wid = (lin & 7) * PER_XCD + (lin >> 3);
  const int y     = wid % H_;
  const int t     = wid / H_;          // 0..23
  const int chalf = t & 1;
  const int xt0   = ((t >> 1) % 3) * 64;
  const int b     = t / 6;

  const int tid = threadIdx.x;

  // ---- stage first[b, :, y, xt0..xt0+63] into LDS (coalesced float4) ----
  {
    const float* fbase = first + ((size_t)(b * KK) * H_ + y) * (size_t)W_ + xt0;
    for (int idx = tid; idx < KK * 16; idx += 256) {
      const int k  = idx >> 4;
      const int xi = (idx & 15) << 2;
      *reinterpret_cast<float4*>(&ldsF[k * 64 + xi]) =
          *reinterpret_cast<const float4*>(fbase + (size_t)k * HW + xi);
    }
  }

  const int xg = tid & 15;
  const int cg = tid >> 4;
  const int c0 = chalf * 64 + cg * 4;
  const int x0 = xt0 + xg * 4;

  // per-lane clamped offsets + masks (OOB regions are whole float4s)
  const bool mA = (x0 != 0);
  const bool mE = (x0 + 8 <= W_);
  const int  oa = mA ? x0 - 4 : 0;
  const int  oe = mE ? x0 + 4 : W_ - 8;
  const bool edge = (xt0 != 64);       // block-uniform

  // p-loop bounds hoisted (block-uniform)
  const int pstart = (y >= MD) ? 0 : (MD - y);
  const int pend   = (y + MD < H_) ? DD : (H_ + MD - y);
  const int yy0    = y + pstart - MD;

  const float* secB = second + (size_t)b * C_ * HW;
  const float* rp0 = secB + ((size_t)c0 * H_ + yy0) * (size_t)W_;
  const float* rp1 = rp0 + HW;
  const float* rp2 = rp1 + HW;
  const float* rp3 = rp2 + HW;

  // prologue: group-0 loads in flight while LDS staging drains
  float4 gA0 = *reinterpret_cast<const float4*>(rp0 + oa);
  float4 gM0 = *reinterpret_cast<const float4*>(rp0 + x0);
  float4 gE0 = *reinterpret_cast<const float4*>(rp0 + oe);
  float4 gA1 = *reinterpret_cast<const float4*>(rp1 + oa);
  float4 gM1 = *reinterpret_cast<const float4*>(rp1 + x0);
  float4 gE1 = *reinterpret_cast<const float4*>(rp1 + oe);

  __syncthreads();

  float acc0[4] = {0.f, 0.f, 0.f, 0.f};
  float acc1[4] = {0.f, 0.f, 0.f, 0.f};
  float acc2[4] = {0.f, 0.f, 0.f, 0.f};
  float acc3[4] = {0.f, 0.f, 0.f, 0.f};

  for (int p = pstart; p < pend; ++p) {
    float4 fo[DD];
#pragma unroll
    for (int o = 0; o < DD; ++o)
      fo[o] = *reinterpret_cast<const float4*>(&ldsF[(p * DD + o) * 64 + (xg << 2)]);

    // issue group-1 loads (current p) before consuming group 0
    float4 hA0 = *reinterpret_cast<const float4*>(rp2 + oa);
    float4 hM0 = *reinterpret_cast<const float4*>(rp2 + x0);
    float4 hE0 = *reinterpret_cast<const float4*>(rp2 + oe);
    float4 hA1 = *reinterpret_cast<const float4*>(rp3 + oa);
    float4 hM1 = *reinterpret_cast<const float4*>(rp3 + x0);
    float4 hE1 = *reinterpret_cast<const float4*>(rp3 + oe);

    {  // FMA group 0 (channels c0, c0+1)
      float s[12];
      unpack12(s, gA0, gM0, gE0, edge, mA, mE);
      FMA_GROUP(acc0, s);
      float u[12];
      unpack12(u, gA1, gM1, gE1, edge, mA, mE);
      FMA_GROUP(acc1, u);
    }

    // advance rows (clamped on last iter: dead but in-bounds reload)
    const int adv = (p + 1 < pend) ? W_ : 0;
    rp0 += adv; rp1 += adv; rp2 += adv; rp3 += adv;

    // prefetch group-0 for next p
    gA0 = *reinterpret_cast<const float4*>(rp0 + oa);
    gM0 = *reinterpret_cast<const float4*>(rp0 + x0);
    gE0 = *reinterpret_cast<const float4*>(rp0 + oe);
    gA1 = *reinterpret_cast<const float4*>(rp1 + oa);
    gM1 = *reinterpret_cast<const float4*>(rp1 + x0);
    gE1 = *reinterpret_cast<const float4*>(rp1 + oe);

    {  // FMA group 1 (channels c0+2, c0+3)
      float s[12];
      unpack12(s, hA0, hM0, hE0, edge, mA, mE);
      FMA_GROUP(acc2, s);
      float u[12];
      unpack12(u, hA1, hM1, hE1, edge, mA, mE);
      FMA_GROUP(acc3, u);
    }
  }

  const float inv_c = 1.0f / (float)C_;
  float* outB = out + (size_t)b * C_ * HW + (size_t)y * W_ + x0;
  {
    float4 v;
    v.x = acc0[0] * inv_c; v.y = acc0[1] * inv_c;
    v.z = acc0[2] * inv_c; v.w = acc0[3] * inv_c;
    *reinterpret_cast<float4*>(outB + (size_t)(c0 + 0) * HW) = v;
    v.x = acc1[0] * inv_c; v.y = acc1[1] * inv_c;
    v.z = acc1[2] * inv_c; v.w = acc1[3] * inv_c;
    *reinterpret_cast<float4*>(outB + (size_t)(c0 + 1) * HW) = v;
    v.x = acc2[0] * inv_c; v.y = acc2[1] * inv_c;
    v.z = acc2[2] * inv_c; v.w = acc2[3] * inv_c;
    *reinterpret_cast<float4*>(outB + (size_t)(c0 + 2) * HW) = v;
    v.x = acc3[0] * inv_c; v.y = acc3[1] * inv_c;
    v.z = acc3[2] * inv_c; v.w = acc3[3] * inv_c;
    *reinterpret_cast<float4*>(outB + (size_t)(c0 + 3) * HW) = v;
  }
}

extern "C" void kernel_launch(void* const* d_in, const int* in_sizes, int n_in,
                              void* d_out, int out_size, void* d_ws, size_t ws_size,
                              hipStream_t stream) {
  const float* first  = (const float*)d_in[0];
  const float* second = (const float*)d_in[1];
  float* out = (float*)d_out;

  corr_transpose_kernel<<<dim3(NWG), 256, 0, stream>>>(first, second, out);
}